// Round 2
// baseline (160.236 us; speedup 1.0000x reference)
//
#include <hip/hip_runtime.h>
#include <hip/hip_bf16.h>
#include <cstdint>
#include <cstddef>

// Problem constants
#define BB 8192
#define UU 512
#define KPACK 1024   // D + U
#define NPACK 2048   // 4*U

using frag16 = __attribute__((ext_vector_type(8))) short;   // 8 bf16 = 16 B (4 VGPRs)
using f32x4  = __attribute__((ext_vector_type(4))) float;

__device__ inline unsigned short f2bf(float f) {
  union { float f; unsigned u; } v; v.f = f;
  unsigned r = v.u + 0x7fffu + ((v.u >> 16) & 1u);   // RNE
  return (unsigned short)(r >> 16);
}

__device__ inline float fast_sigmoid(float x) { return 1.0f / (1.0f + __expf(-x)); }
__device__ inline float fast_tanh(float x) {
  x = fminf(fmaxf(x, -15.f), 15.f);
  float e = __expf(-2.0f * x);
  return (1.0f - e) / (1.0f + e);
}

// ---- merged pack kernel ----
// blocks [0, 4096): pack A = [x | h] -> bf16 [8192][1024] row-major
// blocks [4096, 4608): pack B^T: Bt[n][k] = concat(W,R)[k][n], bf16 [2048][1024]
__global__ __launch_bounds__(256) void pack_kernel(const float* __restrict__ x,
                                                   const float* __restrict__ h,
                                                   const float* __restrict__ W,
                                                   const float* __restrict__ R,
                                                   short* __restrict__ Xp,
                                                   short* __restrict__ Bt) {
  if (blockIdx.x < 4096) {
    int idx = blockIdx.x * 256 + threadIdx.x;
    int row = idx >> 7;             // /128 chunks per row
    int k8  = (idx & 127) << 3;     // 0..1016  (wave-uniform x/h split)
    const float* src = (k8 < 512) ? (x + (size_t)row * 512 + k8)
                                  : (h + (size_t)row * 512 + (k8 - 512));
    float4 a = *(const float4*)(src);
    float4 b = *(const float4*)(src + 4);
    frag16 o;
    o[0] = f2bf(a.x); o[1] = f2bf(a.y); o[2] = f2bf(a.z); o[3] = f2bf(a.w);
    o[4] = f2bf(b.x); o[5] = f2bf(b.y); o[6] = f2bf(b.z); o[7] = f2bf(b.w);
    *(frag16*)(Xp + ((size_t)idx << 3)) = o;
  } else {
    __shared__ float tile[64][65];   // +1 pad: conflict-free transpose
    int b2 = blockIdx.x - 4096;      // 512 blocks: 32 n-tiles x 16 k-tiles
    int nb = (b2 & 31) * 64;
    int kb = (b2 >> 5) * 64;
    int t  = threadIdx.x;
#pragma unroll
    for (int rep = 0; rep < 16; ++rep) {
      int kr = rep * 4 + (t >> 6);
      int c  = t & 63;
      int kg = kb + kr;
      const float* s = (kg < 512) ? (W + (size_t)kg * 2048) : (R + (size_t)(kg - 512) * 2048);
      tile[c][kr] = s[nb + c];
    }
    __syncthreads();
#pragma unroll
    for (int rep = 0; rep < 4; ++rep) {
      int nn = rep * 16 + (t >> 4);
      int k4 = (t & 15) << 2;
      ushort4 o;
      o.x = f2bf(tile[nn][k4 + 0]);
      o.y = f2bf(tile[nn][k4 + 1]);
      o.z = f2bf(tile[nn][k4 + 2]);
      o.w = f2bf(tile[nn][k4 + 3]);
      *(ushort4*)(Bt + (size_t)(nb + nn) * 1024 + kb + k4) = o;
    }
  }
}

// ---- fused GEMM + LSTM pointwise ----
// Tile: BM=128 (batch) x 32 units x 4 gates (=128 N cols). 4 waves: wm = wave&1
// (rows), wn = wave>>1 (16-unit group). Wave fragment-column j == gate j, so all
// 4 gates of unit u sit in the same lane -> pointwise epilogue is lane-local.
__global__ __launch_bounds__(256, 4) void lstm_mfma_kernel(
    const short* __restrict__ A,     // bf16 [8192][1024]
    const short* __restrict__ Bt,    // bf16 [2048][1024], row n = z column
    const float* __restrict__ bias,  // [2048]
    const float* __restrict__ cprev, // [8192][512]
    float* __restrict__ out)         // h, h, c concatenated
{
  __shared__ short lds_a[128 * 64];
  __shared__ short lds_b[128 * 64];

  const int tid  = threadIdx.x;
  const int lane = tid & 63;
  const int wave = tid >> 6;
  const int wm = wave & 1, wn = wave >> 1;
  const int bm = blockIdx.x;   // 64
  const int bn = blockIdx.y;   // 16

  // staging decomposition: 8 lanes per 128B row, xor-swizzle k-chunks.
  const int r8  = lane >> 3;
  const int kg  = lane & 7;
  const int kgx = kg ^ r8;

  const short* ga[4];
  const short* gb[4];
  int ls_off[4];
#pragma unroll
  for (int t = 0; t < 4; ++t) {
    int rowl = wave * 32 + t * 8 + r8;   // local row 0..127
    ga[t] = A + (size_t)(bm * 128 + rowl) * 1024 + kgx * 8;
    int u    = bn * 32 + ((rowl >> 6) << 4) + (rowl & 15);
    int gate = (rowl >> 4) & 3;
    gb[t] = Bt + (size_t)(gate * 512 + u) * 1024 + kgx * 8;
    ls_off[t] = (wave * 32 + t * 8) * 64;
  }

  const int q   = lane >> 4;
  const int c16 = lane & 15;
  const int mx  = c16 & 7;

  // ---- prefetch cprev + bias into registers BEFORE the K-loop: the 16 MB
  // c_tm1 read latency (HBM ~900 cyc) is absorbed by the first barrier's
  // vmcnt(0) drain instead of stalling every lane in the epilogue. ----
  const int u = bn * 32 + wn * 16 + c16;
  const float b0 = bias[u];
  const float b1 = bias[512 + u];
  const float b2 = bias[1024 + u];
  const float b3 = bias[1536 + u];
  float cp[4][4];
#pragma unroll
  for (int i = 0; i < 4; ++i) {
    int row0 = bm * 128 + wm * 64 + i * 16 + q * 4;
#pragma unroll
    for (int r = 0; r < 4; ++r)
      cp[i][r] = cprev[(size_t)(row0 + r) * UU + u];
  }

  f32x4 acc[4][4];
#pragma unroll
  for (int i = 0; i < 4; ++i)
#pragma unroll
    for (int j = 0; j < 4; ++j)
      acc[i][j] = f32x4{0.f, 0.f, 0.f, 0.f};

  for (int kt = 0; kt < 16; ++kt) {
    const int k0 = kt * 64;
#pragma unroll
    for (int t = 0; t < 4; ++t)
      __builtin_amdgcn_global_load_lds(
          (const __attribute__((address_space(1))) void*)(ga[t] + k0),
          (__attribute__((address_space(3))) void*)(lds_a + ls_off[t]), 16, 0, 0);
#pragma unroll
    for (int t = 0; t < 4; ++t)
      __builtin_amdgcn_global_load_lds(
          (const __attribute__((address_space(1))) void*)(gb[t] + k0),
          (__attribute__((address_space(3))) void*)(lds_b + ls_off[t]), 16, 0, 0);
    __syncthreads();   // compiler emits vmcnt(0) drain here
#pragma unroll
    for (int s = 0; s < 2; ++s) {
      const int kch = (((s << 2) + q) ^ mx) << 3;
      frag16 af[4], bf[4];
#pragma unroll
      for (int i = 0; i < 4; ++i)
        af[i] = *(const frag16*)(lds_a + (wm * 64 + i * 16 + c16) * 64 + kch);
#pragma unroll
      for (int j = 0; j < 4; ++j)
        bf[j] = *(const frag16*)(lds_b + (wn * 64 + j * 16 + c16) * 64 + kch);
#pragma unroll
      for (int i = 0; i < 4; ++i)
#pragma unroll
        for (int j = 0; j < 4; ++j)
          acc[i][j] = __builtin_amdgcn_mfma_f32_16x16x32_bf16(af[i], bf[j], acc[i][j], 0, 0, 0);
    }
    __syncthreads();
  }

  // epilogue: lane-local LSTM pointwise. col=lane&15 -> unit, frag col j -> gate.
  float* outh0 = out;
  float* outh1 = out + (size_t)BB * UU;
  float* outc  = out + (size_t)2 * BB * UU;

#pragma unroll
  for (int i = 0; i < 4; ++i) {
    int row0 = bm * 128 + wm * 64 + i * 16 + q * 4;
#pragma unroll
    for (int r = 0; r < 4; ++r) {
      size_t off = (size_t)(row0 + r) * UU + u;
      float z0 = acc[i][0][r] + b0;
      float z1 = acc[i][1][r] + b1;
      float z2 = acc[i][2][r] + b2;
      float z3 = acc[i][3][r] + b3;
      float ig = fast_sigmoid(z0);
      float fg = fast_sigmoid(z1);
      float gg = fast_tanh(z2);
      float og = fast_sigmoid(z3);
      float cc = fg * cp[i][r] + ig * gg;
      float hh = og * fast_tanh(cc);
      outh0[off] = hh;
      outh1[off] = hh;
      outc[off]  = cc;
    }
  }
}

extern "C" void kernel_launch(void* const* d_in, const int* in_sizes, int n_in,
                              void* d_out, int out_size, void* d_ws, size_t ws_size,
                              hipStream_t stream) {
  const float* x  = (const float*)d_in[0];
  const float* h  = (const float*)d_in[1];
  const float* c  = (const float*)d_in[2];
  const float* W  = (const float*)d_in[3];
  const float* R  = (const float*)d_in[4];
  const float* b  = (const float*)d_in[5];
  float* out = (float*)d_out;

  short* Xp = (short*)d_ws;                        // 16 MB bf16 [8192][1024]
  short* Bt = Xp + (size_t)BB * KPACK;             // 4 MB  bf16 [2048][1024]

  pack_kernel<<<4608, 256, 0, stream>>>(x, h, W, R, Xp, Bt);
  lstm_mfma_kernel<<<dim3(64, 16), 256, 0, stream>>>(Xp, Bt, b, c, out);
}

// Round 3
// 153.454 us; speedup vs baseline: 1.0442x; 1.0442x over previous
//
#include <hip/hip_runtime.h>
#include <hip/hip_bf16.h>
#include <cstdint>
#include <cstddef>

// Problem constants
#define BB 8192
#define UU 512
#define KPACK 1024   // D + U
#define NPACK 2048   // 4*U

using frag16 = __attribute__((ext_vector_type(8))) short;   // 8 bf16 = 16 B (4 VGPRs)
using f32x4  = __attribute__((ext_vector_type(4))) float;

__device__ inline unsigned short f2bf(float f) {
  union { float f; unsigned u; } v; v.f = f;
  unsigned r = v.u + 0x7fffu + ((v.u >> 16) & 1u);   // RNE
  return (unsigned short)(r >> 16);
}

__device__ inline float fast_sigmoid(float x) { return 1.0f / (1.0f + __expf(-x)); }
__device__ inline float fast_tanh(float x) {
  x = fminf(fmaxf(x, -15.f), 15.f);
  float e = __expf(-2.0f * x);
  return (1.0f - e) / (1.0f + e);
}

// ---- merged pack kernel ----
// blocks [0, 4096): pack A = [x | h] -> bf16 [8192][1024] row-major
// blocks [4096, 4608): pack B^T: Bt[n][k] = concat(W,R)[k][n], bf16 [2048][1024]
__global__ __launch_bounds__(256) void pack_kernel(const float* __restrict__ x,
                                                   const float* __restrict__ h,
                                                   const float* __restrict__ W,
                                                   const float* __restrict__ R,
                                                   short* __restrict__ Xp,
                                                   short* __restrict__ Bt) {
  if (blockIdx.x < 4096) {
    int idx = blockIdx.x * 256 + threadIdx.x;
    int row = idx >> 7;             // /128 chunks per row
    int k8  = (idx & 127) << 3;     // 0..1016  (wave-uniform x/h split)
    const float* src = (k8 < 512) ? (x + (size_t)row * 512 + k8)
                                  : (h + (size_t)row * 512 + (k8 - 512));
    float4 a = *(const float4*)(src);
    float4 b = *(const float4*)(src + 4);
    frag16 o;
    o[0] = f2bf(a.x); o[1] = f2bf(a.y); o[2] = f2bf(a.z); o[3] = f2bf(a.w);
    o[4] = f2bf(b.x); o[5] = f2bf(b.y); o[6] = f2bf(b.z); o[7] = f2bf(b.w);
    *(frag16*)(Xp + ((size_t)idx << 3)) = o;
  } else {
    __shared__ float tile[64][65];   // +1 pad: conflict-free transpose
    int b2 = blockIdx.x - 4096;      // 512 blocks: 32 n-tiles x 16 k-tiles
    int nb = (b2 & 31) * 64;
    int kb = (b2 >> 5) * 64;
    int t  = threadIdx.x;
#pragma unroll
    for (int rep = 0; rep < 16; ++rep) {
      int kr = rep * 4 + (t >> 6);
      int c  = t & 63;
      int kg = kb + kr;
      const float* s = (kg < 512) ? (W + (size_t)kg * 2048) : (R + (size_t)(kg - 512) * 2048);
      tile[c][kr] = s[nb + c];
    }
    __syncthreads();
#pragma unroll
    for (int rep = 0; rep < 4; ++rep) {
      int nn = rep * 16 + (t >> 4);
      int k4 = (t & 15) << 2;
      ushort4 o;
      o.x = f2bf(tile[nn][k4 + 0]);
      o.y = f2bf(tile[nn][k4 + 1]);
      o.z = f2bf(tile[nn][k4 + 2]);
      o.w = f2bf(tile[nn][k4 + 3]);
      *(ushort4*)(Bt + (size_t)(nb + nn) * 1024 + kb + k4) = o;
    }
  }
}

// ---- fused GEMM + LSTM pointwise ----
// Block tile: 256 (batch) x 128 N-cols (4 gates x 32 units). 4 waves, each
// owning a 64x128 slab (wave w -> rows w*64..w*64+63): A-tile LDS-read 1x,
// B-tile 4x => 96 KB LDS reads per block-kt vs 128 KB for 2x2/64x64 (-25%).
// N-local col = gate*16-interleaved: frag j -> gate j&3, unit grp j>>2, so all
// 4 gates of unit u sit in the same lane -> lane-local LSTM epilogue.
__global__ __launch_bounds__(256, 2) void lstm_mfma_kernel(
    const short* __restrict__ A,     // bf16 [8192][1024]
    const short* __restrict__ Bt,    // bf16 [2048][1024], row n = z column
    const float* __restrict__ bias,  // [2048]
    const float* __restrict__ cprev, // [8192][512]
    float* __restrict__ out)         // h, h, c concatenated
{
  __shared__ short lds_a[256 * 64];  // 32 KB
  __shared__ short lds_b[128 * 64];  // 16 KB

  const int tid  = threadIdx.x;
  const int lane = tid & 63;
  const int wave = tid >> 6;
  const int bm = blockIdx.x;   // 32
  const int bn = blockIdx.y;   // 16

  // staging decomposition: 8 lanes per 128B k-row, xor-swizzle k-chunks by
  // (row&7) so LDS slot kg holds global chunk kg^(row&7).
  const int r8  = lane >> 3;
  const int kg  = lane & 7;
  const int kgx = kg ^ r8;

  const short* ga[8];   // wave stages its own 64 A-rows: 8 instrs x 8 rows
  const short* gb[4];   // wave stages 32 B-rows: 4 instrs x 8 rows
  int lsa_off[8], lsb_off[4];
#pragma unroll
  for (int t = 0; t < 8; ++t) {
    int rowl = wave * 64 + t * 8 + r8;   // local A row 0..255
    ga[t] = A + (size_t)(bm * 256 + rowl) * 1024 + kgx * 8;
    lsa_off[t] = (wave * 64 + t * 8) * 64;
  }
#pragma unroll
  for (int t = 0; t < 4; ++t) {
    int rowl = wave * 32 + t * 8 + r8;   // local B row (n-local) 0..127
    int u    = bn * 32 + ((rowl >> 6) << 4) + (rowl & 15);
    int gate = (rowl >> 4) & 3;
    gb[t] = Bt + (size_t)(gate * 512 + u) * 1024 + kgx * 8;
    lsb_off[t] = (wave * 32 + t * 8) * 64;
  }

  const int q   = lane >> 4;
  const int c16 = lane & 15;
  const int mx  = c16 & 7;

  f32x4 acc[4][8];
#pragma unroll
  for (int i = 0; i < 4; ++i)
#pragma unroll
    for (int j = 0; j < 8; ++j)
      acc[i][j] = f32x4{0.f, 0.f, 0.f, 0.f};

  for (int kt = 0; kt < 16; ++kt) {
    const int k0 = kt * 64;
#pragma unroll
    for (int t = 0; t < 8; ++t)
      __builtin_amdgcn_global_load_lds(
          (const __attribute__((address_space(1))) void*)(ga[t] + k0),
          (__attribute__((address_space(3))) void*)(lds_a + lsa_off[t]), 16, 0, 0);
#pragma unroll
    for (int t = 0; t < 4; ++t)
      __builtin_amdgcn_global_load_lds(
          (const __attribute__((address_space(1))) void*)(gb[t] + k0),
          (__attribute__((address_space(3))) void*)(lds_b + lsb_off[t]), 16, 0, 0);
    __syncthreads();   // vmcnt(0) drain
#pragma unroll
    for (int s = 0; s < 2; ++s) {
      const int kch = (((s << 2) + q) ^ mx) << 3;
      frag16 af[4], bf[8];
#pragma unroll
      for (int i = 0; i < 4; ++i)
        af[i] = *(const frag16*)(lds_a + (wave * 64 + i * 16 + c16) * 64 + kch);
#pragma unroll
      for (int j = 0; j < 8; ++j)
        bf[j] = *(const frag16*)(lds_b + (j * 16 + c16) * 64 + kch);
#pragma unroll
      for (int i = 0; i < 4; ++i)
#pragma unroll
        for (int j = 0; j < 8; ++j)
          acc[i][j] = __builtin_amdgcn_mfma_f32_16x16x32_bf16(af[i], bf[j], acc[i][j], 0, 0, 0);
    }
    __syncthreads();
  }

  // epilogue: lane-local LSTM pointwise. frag j -> gate j&3, unit grp j>>2.
  float* outh0 = out;
  float* outh1 = out + (size_t)BB * UU;
  float* outc  = out + (size_t)2 * BB * UU;

#pragma unroll
  for (int uu = 0; uu < 2; ++uu) {
    const int u = bn * 32 + uu * 16 + c16;
    const float b0 = bias[u];
    const float b1 = bias[512 + u];
    const float b2 = bias[1024 + u];
    const float b3 = bias[1536 + u];
#pragma unroll
    for (int i = 0; i < 4; ++i) {
      int row0 = bm * 256 + wave * 64 + i * 16 + q * 4;
#pragma unroll
      for (int r = 0; r < 4; ++r) {
        size_t off = (size_t)(row0 + r) * UU + u;
        float z0 = acc[i][uu * 4 + 0][r] + b0;
        float z1 = acc[i][uu * 4 + 1][r] + b1;
        float z2 = acc[i][uu * 4 + 2][r] + b2;
        float z3 = acc[i][uu * 4 + 3][r] + b3;
        float ig = fast_sigmoid(z0);
        float fg = fast_sigmoid(z1);
        float gg = fast_tanh(z2);
        float og = fast_sigmoid(z3);
        float cp = cprev[off];
        float cc = fg * cp + ig * gg;
        float hh = og * fast_tanh(cc);
        outh0[off] = hh;
        outh1[off] = hh;
        outc[off]  = cc;
      }
    }
  }
}

extern "C" void kernel_launch(void* const* d_in, const int* in_sizes, int n_in,
                              void* d_out, int out_size, void* d_ws, size_t ws_size,
                              hipStream_t stream) {
  const float* x  = (const float*)d_in[0];
  const float* h  = (const float*)d_in[1];
  const float* c  = (const float*)d_in[2];
  const float* W  = (const float*)d_in[3];
  const float* R  = (const float*)d_in[4];
  const float* b  = (const float*)d_in[5];
  float* out = (float*)d_out;

  short* Xp = (short*)d_ws;                        // 16 MB bf16 [8192][1024]
  short* Bt = Xp + (size_t)BB * KPACK;             // 4 MB  bf16 [2048][1024]

  pack_kernel<<<4608, 256, 0, stream>>>(x, h, W, R, Xp, Bt);
  lstm_mfma_kernel<<<dim3(32, 16), 256, 0, stream>>>(Xp, Bt, b, c, out);
}

// Round 4
// 146.904 us; speedup vs baseline: 1.0908x; 1.0446x over previous
//
#include <hip/hip_runtime.h>
#include <hip/hip_bf16.h>
#include <cstdint>
#include <cstddef>

// Problem constants
#define BB 8192
#define UU 512
#define KPACK 1024   // D + U
#define NPACK 2048   // 4*U

using frag16 = __attribute__((ext_vector_type(8))) short;   // 8 bf16 = 16 B (4 VGPRs)
using f32x4  = __attribute__((ext_vector_type(4))) float;

__device__ inline float fast_sigmoid(float x) { return 1.0f / (1.0f + __expf(-x)); }
__device__ inline float fast_tanh(float x) {
  x = fminf(fmaxf(x, -15.f), 15.f);
  float e = __expf(-2.0f * x);
  return (1.0f - e) / (1.0f + e);
}

// packed RNE f32x2 -> bf16x2 (v_cvt_pk_bf16_f32 on gfx950 via hip_bf16.h)
__device__ inline unsigned cvt2(float lo, float hi) {
  __hip_bfloat162 b = __float22bfloat162_rn(float2{lo, hi});
  union { __hip_bfloat162 b; unsigned u; } v; v.b = b;
  return v.u;
}

// ---- merged pack kernel ----
// blocks [0, 4096): pack A = [x | h] -> bf16 [8192][1024] row-major
// blocks [4096, 4608): pack B^T: Bt[n][k] = concat(W,R)[k][n], bf16 [2048][1024]
// Packed converts: 4 v_cvt_pk_bf16_f32 per 8 elems (was ~32 scalar VALU ops ->
// pack_a was VALU-bound at ~27 us; now memory-bound ~10 us).
__global__ __launch_bounds__(256) void pack_kernel(const float* __restrict__ x,
                                                   const float* __restrict__ h,
                                                   const float* __restrict__ W,
                                                   const float* __restrict__ R,
                                                   short* __restrict__ Xp,
                                                   short* __restrict__ Bt) {
  if (blockIdx.x < 4096) {
    int idx = blockIdx.x * 256 + threadIdx.x;
    int row = idx >> 7;             // /128 chunks per row
    int k8  = (idx & 127) << 3;     // 0..1016  (wave-uniform x/h split)
    const float* src = (k8 < 512) ? (x + (size_t)row * 512 + k8)
                                  : (h + (size_t)row * 512 + (k8 - 512));
    float4 a = *(const float4*)(src);
    float4 b = *(const float4*)(src + 4);
    uint4 o;
    o.x = cvt2(a.x, a.y);
    o.y = cvt2(a.z, a.w);
    o.z = cvt2(b.x, b.y);
    o.w = cvt2(b.z, b.w);
    *(uint4*)(Xp + ((size_t)idx << 3)) = o;
  } else {
    __shared__ float tile[64][65];   // +1 pad: conflict-free transpose
    int b2 = blockIdx.x - 4096;      // 512 blocks: 32 n-tiles x 16 k-tiles
    int nb = (b2 & 31) * 64;
    int kb = (b2 >> 5) * 64;
    int t  = threadIdx.x;
#pragma unroll
    for (int rep = 0; rep < 16; ++rep) {
      int kr = rep * 4 + (t >> 6);
      int c  = t & 63;
      int kg = kb + kr;
      const float* s = (kg < 512) ? (W + (size_t)kg * 2048) : (R + (size_t)(kg - 512) * 2048);
      tile[c][kr] = s[nb + c];
    }
    __syncthreads();
#pragma unroll
    for (int rep = 0; rep < 4; ++rep) {
      int nn = rep * 16 + (t >> 4);
      int k4 = (t & 15) << 2;
      uint2 o;
      o.x = cvt2(tile[nn][k4 + 0], tile[nn][k4 + 1]);
      o.y = cvt2(tile[nn][k4 + 2], tile[nn][k4 + 3]);
      *(uint2*)(Bt + (size_t)(nb + nn) * 1024 + kb + k4) = o;
    }
  }
}

// ---- fused GEMM + LSTM pointwise (R1 config: best measured, 51.5 us) ----
// Tile: BM=128 (batch) x 32 units x 4 gates (=128 N cols). 4 waves: wm = wave&1
// (rows), wn = wave>>1 (16-unit group). Wave fragment-column j == gate j, so all
// 4 gates of unit u sit in the same lane -> pointwise epilogue is lane-local.
// 32 KB LDS + 64 VGPR -> 4 blocks/CU. Do NOT hold cprev in regs across the
// K-loop (R2: spilled, +46 MB HBM traffic).
__global__ __launch_bounds__(256, 4) void lstm_mfma_kernel(
    const short* __restrict__ A,     // bf16 [8192][1024]
    const short* __restrict__ Bt,    // bf16 [2048][1024], row n = z column
    const float* __restrict__ bias,  // [2048]
    const float* __restrict__ cprev, // [8192][512]
    float* __restrict__ out)         // h, h, c concatenated
{
  __shared__ short lds_a[128 * 64];
  __shared__ short lds_b[128 * 64];

  const int tid  = threadIdx.x;
  const int lane = tid & 63;
  const int wave = tid >> 6;
  const int wm = wave & 1, wn = wave >> 1;
  const int bm = blockIdx.x;   // 64
  const int bn = blockIdx.y;   // 16

  // staging decomposition: 8 lanes per 128B row, xor-swizzle k-chunks.
  const int r8  = lane >> 3;
  const int kg  = lane & 7;
  const int kgx = kg ^ r8;

  const short* ga[4];
  const short* gb[4];
  int ls_off[4];
#pragma unroll
  for (int t = 0; t < 4; ++t) {
    int rowl = wave * 32 + t * 8 + r8;   // local row 0..127
    ga[t] = A + (size_t)(bm * 128 + rowl) * 1024 + kgx * 8;
    int u    = bn * 32 + ((rowl >> 6) << 4) + (rowl & 15);
    int gate = (rowl >> 4) & 3;
    gb[t] = Bt + (size_t)(gate * 512 + u) * 1024 + kgx * 8;
    ls_off[t] = (wave * 32 + t * 8) * 64;
  }

  const int q   = lane >> 4;
  const int c16 = lane & 15;
  const int mx  = c16 & 7;

  f32x4 acc[4][4];
#pragma unroll
  for (int i = 0; i < 4; ++i)
#pragma unroll
    for (int j = 0; j < 4; ++j)
      acc[i][j] = f32x4{0.f, 0.f, 0.f, 0.f};

  for (int kt = 0; kt < 16; ++kt) {
    const int k0 = kt * 64;
#pragma unroll
    for (int t = 0; t < 4; ++t)
      __builtin_amdgcn_global_load_lds(
          (const __attribute__((address_space(1))) void*)(ga[t] + k0),
          (__attribute__((address_space(3))) void*)(lds_a + ls_off[t]), 16, 0, 0);
#pragma unroll
    for (int t = 0; t < 4; ++t)
      __builtin_amdgcn_global_load_lds(
          (const __attribute__((address_space(1))) void*)(gb[t] + k0),
          (__attribute__((address_space(3))) void*)(lds_b + ls_off[t]), 16, 0, 0);
    __syncthreads();   // compiler emits vmcnt(0) drain here
#pragma unroll
    for (int s = 0; s < 2; ++s) {
      const int kch = (((s << 2) + q) ^ mx) << 3;
      frag16 af[4], bf[4];
#pragma unroll
      for (int i = 0; i < 4; ++i)
        af[i] = *(const frag16*)(lds_a + (wm * 64 + i * 16 + c16) * 64 + kch);
#pragma unroll
      for (int j = 0; j < 4; ++j)
        bf[j] = *(const frag16*)(lds_b + (wn * 64 + j * 16 + c16) * 64 + kch);
#pragma unroll
      for (int i = 0; i < 4; ++i)
#pragma unroll
        for (int j = 0; j < 4; ++j)
          acc[i][j] = __builtin_amdgcn_mfma_f32_16x16x32_bf16(af[i], bf[j], acc[i][j], 0, 0, 0);
    }
    __syncthreads();
  }

  // epilogue: lane-local LSTM pointwise. col=lane&15 -> unit, frag col j -> gate.
  const int u = bn * 32 + wn * 16 + c16;
  const float b0 = bias[u];
  const float b1 = bias[512 + u];
  const float b2 = bias[1024 + u];
  const float b3 = bias[1536 + u];
  float* outh0 = out;
  float* outh1 = out + (size_t)BB * UU;
  float* outc  = out + (size_t)2 * BB * UU;

#pragma unroll
  for (int i = 0; i < 4; ++i) {
    int row0 = bm * 128 + wm * 64 + i * 16 + q * 4;
#pragma unroll
    for (int r = 0; r < 4; ++r) {
      size_t off = (size_t)(row0 + r) * UU + u;
      float z0 = acc[i][0][r] + b0;
      float z1 = acc[i][1][r] + b1;
      float z2 = acc[i][2][r] + b2;
      float z3 = acc[i][3][r] + b3;
      float ig = fast_sigmoid(z0);
      float fg = fast_sigmoid(z1);
      float gg = fast_tanh(z2);
      float og = fast_sigmoid(z3);
      float cp = cprev[off];
      float cc = fg * cp + ig * gg;
      float hh = og * fast_tanh(cc);
      outh0[off] = hh;
      outh1[off] = hh;
      outc[off]  = cc;
    }
  }
}

extern "C" void kernel_launch(void* const* d_in, const int* in_sizes, int n_in,
                              void* d_out, int out_size, void* d_ws, size_t ws_size,
                              hipStream_t stream) {
  const float* x  = (const float*)d_in[0];
  const float* h  = (const float*)d_in[1];
  const float* c  = (const float*)d_in[2];
  const float* W  = (const float*)d_in[3];
  const float* R  = (const float*)d_in[4];
  const float* b  = (const float*)d_in[5];
  float* out = (float*)d_out;

  short* Xp = (short*)d_ws;                        // 16 MB bf16 [8192][1024]
  short* Bt = Xp + (size_t)BB * KPACK;             // 4 MB  bf16 [2048][1024]

  pack_kernel<<<4608, 256, 0, stream>>>(x, h, W, R, Xp, Bt);
  lstm_mfma_kernel<<<dim3(64, 16), 256, 0, stream>>>(Xp, Bt, b, c, out);
}